// Round 1
// baseline (469.002 us; speedup 1.0000x reference)
//
#include <hip/hip_runtime.h>
#include <hip/hip_fp16.h>

// RNNModel: B=2048 seqs, T=2048 steps, tiny 4-dim tanh RNN.
// Dtype-adaptive (fp32 vs bf16 probe per kernel, wave-0 ballot on x[0:256B]).
// 2 kernels:
//  k_xi:   x->xi, LDS-staged coalesced reads, per-block const fusion,
//          stores xi as packed fp16 [t4][b][j][ti] (prescaled by 2*log2e).
//  k_scan: 128 blocks x 128 threads (2 waves).
//          wave0: 4 lanes/seq recurrence, DPP quad xor shuffles,
//                 r = 1/(1+2^z'), h = 1-2r, D=8 prefetch; h handed to wave1
//                 via 8-slot LDS ring (no global h traffic at all).
//          wave1: consumes ring, quad-transposes h via 3 DPPs + dynamic
//                 halfword extract, runs Dense(6)+relu+Dense(1), stores out.
//          Intra-block ring protocol: DS ops complete in order per wave, so
//          data-write -> flag-write needs only a compiler barrier.
// ws: [0,33.5MB) xi fp16.  (hbuf eliminated.)

using u32 = unsigned int;
using u16 = unsigned short;

#define B_N 2048
#define T_N 2048

typedef __fp16 f16x2 __attribute__((ext_vector_type(2)));

__device__ __forceinline__ float bfh(u16 v){ return __uint_as_float(((u32)v) << 16); }
__device__ __forceinline__ float lo16(u32 u){ return __uint_as_float(u << 16); }
__device__ __forceinline__ float hi16(u32 u){ return __uint_as_float(u & 0xFFFF0000u); }
__device__ __forceinline__ u16 f2bf(float f){
  u32 u = __float_as_uint(f);
  return (u16)((u + 0x7FFFu + ((u >> 16) & 1u)) >> 16);
}
__device__ __forceinline__ u32 pk2(float a, float b){
  union { f16x2 h; u32 u; } cv;
  cv.h = __builtin_amdgcn_cvt_pkrtz(a, b);
  return cv.u;
}
__device__ __forceinline__ float xlo(u32 w){ return __half2float(__ushort_as_half((u16)(w & 0xFFFFu))); }
__device__ __forceinline__ float xhi(u32 w){ return __half2float(__ushort_as_half((u16)(w >> 16))); }

#define S_PRE 2.8853900817779268f     // 2*log2(e)
#define S_NEG (-5.7707801635558537f)  // -2*S

// Wave-0 dtype probe: even u16s of x; bf16 N(0,1) exp in [110,140] ~99%,
// fp32 low-mantissa halves ~12%. Call with full wave active.
__device__ __forceinline__ bool probe_f32(const void* xraw, int lane){
  const u16* xu = (const u16*)xraw;
  u32 e = (xu[2*lane] >> 7) & 0xFF;
  unsigned long long m = __ballot(e >= 110 && e <= 140);
  return __popcll(m) < 32;
}
__device__ __forceinline__ float ldsel(const void* p, int i, bool f32){
  return f32 ? ((const float*)p)[i] : bfh(((const u16*)p)[i]);
}

// k_xi: block tile 8 b x 128 t, grid 4096. Wave 0 builds fused consts in LDS:
//   W1f[48] (@0), Wc[16]=S*(W2@Wi) (@48), bc[4]=S*(b2@Wi+bi)+S*colsum(Wh) (@64),
//   pre1[8][4]=b1+embed[b]@W1[12:16] (@68), flag (@100).
// Then stage x rows into LDS (coalesced uint4), compute, store packed fp16 xi.
__global__ __launch_bounds__(256) void k_xi(const void* __restrict__ xraw,
                                            const void* __restrict__ embed,
                                            const void* __restrict__ W1,
                                            const void* __restrict__ b1,
                                            const void* __restrict__ W2,
                                            const void* __restrict__ b2,
                                            const void* __restrict__ Wi,
                                            const void* __restrict__ bi,
                                            const void* __restrict__ Wh,
                                            u32* __restrict__ xi2)
{
  __shared__ u32 sx[12320];            // 8 rows x 1540 u32 (fp32 worst case)
  __shared__ float sc[104];
  const int tid = threadIdx.x;
  const int b0 = (blockIdx.x >> 4) << 3;        // 256 b-tiles of 8
  const int t0 = (blockIdx.x & 15) << 7;        // 16 t-tiles of 128

  if (tid < 64) {
    const bool f32 = probe_f32(xraw, tid);
    if (tid == 0) sc[100] = f32 ? 1.0f : 0.0f;
    if (tid < 48) sc[tid] = ldsel(W1, tid, f32);
    else {                            // Wc = S*(W2@Wi)
      int i = tid - 48, r = i >> 2, c = i & 3;
      float s = 0.f;
      for (int p = 0; p < 4; ++p) s += ldsel(W2, r*4+p, f32) * ldsel(Wi, p*4+c, f32);
      sc[48 + i] = S_PRE * s;
    }
    if (tid < 4) {                    // bc
      int c = tid;
      float s = ldsel(bi, c, f32);
      for (int p = 0; p < 4; ++p) s += ldsel(b2, p, f32) * ldsel(Wi, p*4+c, f32);
      float sw = 0.f;
      for (int k = 0; k < 4; ++k) sw += ldsel(Wh, k*4+c, f32);
      sc[64 + c] = S_PRE * (s + sw);
    }
    if (tid < 32) {                   // pre1 for this block's 8 b's
      int r = tid >> 2, c = tid & 3;
      int b = b0 + r;
      float s = ldsel(b1, c, f32);
      for (int e = 0; e < 4; ++e)
        s += ldsel(embed, b*4+e, f32) * ldsel(W1, (12+e)*4+c, f32);
      sc[68 + tid] = s;
    }
  }
  __syncthreads();
  const bool f32 = sc[100] > 0.5f;

  const int RS  = f32 ? 1540 : 772;   // LDS row stride (u32), 16B-aligned
  const int CPT = f32 ? 12 : 6;       // u32 per t
  const int K   = f32 ? 12 : 6;       // uint4 per staging thread

  { // stage: row r = tid>>5, 32 threads/row
    const int r = tid >> 5, c = tid & 31;
    const size_t rowbase_u32 = ((size_t)(b0 + r) * T_N + t0) * (size_t)CPT;
    const uint4* gsrc = (const uint4*)((const u32*)xraw + rowbase_u32);
    uint4* ldst = (uint4*)(sx + r * RS);
    for (int k = 0; k < K; ++k)
      ldst[c + 32*k] = gsrc[c + 32*k];
  }
  __syncthreads();

  float W1f[48];
#pragma unroll
  for (int i = 0; i < 48; ++i) W1f[i] = sc[i];
  float Wc[16];
#pragma unroll
  for (int i = 0; i < 16; ++i) Wc[i] = sc[48+i];
  float bc[4];
#pragma unroll
  for (int i = 0; i < 4; ++i) bc[i] = sc[64+i];

  const int r = tid & 7, t4l = tid >> 3;
  const int b = b0 + r;
  const int T4 = (t0 >> 2) + t4l;
  float p1[4];
#pragma unroll
  for (int i = 0; i < 4; ++i) p1[i] = sc[68 + r*4 + i];

  float acc[4][4];   // [j][ti]
#pragma unroll
  for (int ti = 0; ti < 4; ++ti) {
    const u32* sp = sx + r * RS + (t4l*4 + ti) * CPT;
    float xf[12];
    if (f32) {
#pragma unroll
      for (int f = 0; f < 12; ++f) xf[f] = __uint_as_float(sp[f]);
    } else {
#pragma unroll
      for (int w = 0; w < 6; ++w) {
        u32 u = sp[w];
        xf[2*w]   = lo16(u);
        xf[2*w+1] = hi16(u);
      }
    }
    float h1[4];
#pragma unroll
    for (int c = 0; c < 4; ++c) {
      float s = p1[c];
#pragma unroll
      for (int f = 0; f < 12; ++f) s = fmaf(xf[f], W1f[f*4+c], s);
      h1[c] = fmaxf(s, 0.f);
    }
#pragma unroll
    for (int c = 0; c < 4; ++c) {
      float s = bc[c];
#pragma unroll
      for (int k = 0; k < 4; ++k) s = fmaf(h1[k], Wc[k*4+c], s);
      acc[c][ti] = s;
    }
  }
  // pack fp16: [t4][b][j][ti], 32 B per thread, contiguous across r.
  u32 w[8];
#pragma unroll
  for (int j = 0; j < 4; ++j) {
    w[j*2]   = pk2(acc[j][0], acc[j][1]);
    w[j*2+1] = pk2(acc[j][2], acc[j][3]);
  }
  u32* dst = xi2 + ((size_t)T4 * B_N + b) * 8;
  *(uint4*)(dst)     = make_uint4(w[0], w[1], w[2], w[3]);
  *(uint4*)(dst + 4) = make_uint4(w[4], w[5], w[6], w[7]);
}

// DPP quad_perm xor within lane-quads (VALU, off the LDS pipe).
template<int CTRL>
__device__ __forceinline__ float dppf(float v) {
  return __int_as_float(__builtin_amdgcn_mov_dpp(__float_as_int(v), CTRL, 0xF, 0xF, true));
}

// Extract fp16 element `sel` (0..3) of a uint2 (per-lane dynamic index).
__device__ __forceinline__ float sel_h(uint2 v, int sel){
  u32 w = (sel & 2) ? v.y : v.x;
  w >>= ((sel & 1) << 4);
  return __half2float(__ushort_as_half((u16)(w & 0xFFFFu)));
}

// Fused scan + output MLP. 128 blocks x 128 threads (2 waves per block).
// wave0 (tid<64): 4 lanes/seq recurrence; lane j owns component j.
//   r = 1/(1+2^z'), h = 1-2r; z' = base + sum_m Whn[(j^m)][j]*r_{j^m}
//   as an fma tree (~36 cy serial chain), D=8 prefetch of xi.
//   Per t4: 8-B packed fp16 h into LDS ring slot (t4&7), then flag.
// wave1 (tid>=64): spins on flag (cached counter, ~0 polls steady-state),
//   ds_read_b64 its lane's uint2, signals consumption, quad-transposes h
//   (3 DPP xors; W3 rows pre-permuted per lane so weights index statically),
//   computes relu(h@W3+b3)@W4+b4 for t = t4*4 + (lane&3), stores out.
// Steady state: wave1 ~120cy/t4 < wave0 ~150cy/t4 chain -> no backpressure.
__global__ __launch_bounds__(128) void k_scan(const void* __restrict__ xraw,
                                              const void* __restrict__ Wh,
                                              const u32* __restrict__ xi2,
                                              const void* __restrict__ W3,
                                              const void* __restrict__ b3,
                                              const void* __restrict__ W4,
                                              const void* __restrict__ b4,
                                              void* __restrict__ outp)
{
  __shared__ uint2 sring[8][64];
  __shared__ u32 scnt[2];                 // [0]=wr (wave0), [1]=rd (wave1)
  volatile u32* vwr = &scnt[0];
  volatile u32* vrd = &scnt[1];

  const int tid = threadIdx.x;
  const int lane = tid & 63;
  if (tid < 2) scnt[tid] = 0;
  __syncthreads();

  const bool f32 = probe_f32(xraw, lane);   // per-wave uniform

  if (tid < 64) {
    // ---------------- wave0: recurrence ----------------
    const int g = blockIdx.x * 64 + lane;
    const int b = g >> 2, j = g & 3;
    const float u0 = S_NEG * ldsel(Wh, (j<<2) + j, f32);
    const float u1 = S_NEG * ldsel(Wh, ((j^1)<<2) + j, f32);
    const float u2 = S_NEG * ldsel(Wh, ((j^2)<<2) + j, f32);
    const float u3 = S_NEG * ldsel(Wh, ((j^3)<<2) + j, f32);

    const uint2* xp = (const uint2*)xi2 + (size_t)b*4 + j;   // + t4*B_N*4

    constexpr int D = 8;    // 8 t4-groups = 32 steps of prefetch
    uint2 buf[D];
#pragma unroll
    for (int i = 0; i < D; ++i) buf[i] = xp[(size_t)i * (B_N*4)];

    float r = 0.5f;
    u32 rdseen = 0;
    for (int tb = 0; tb < T_N/4; tb += D) {
#pragma unroll
      for (int q = 0; q < D; ++q) {
        const u32 t4i = (u32)(tb + q);
        uint2 xiv = buf[q];
        int pf = tb + q + D; pf = pf < (T_N/4 - 1) ? pf : (T_N/4 - 1);
        buf[q] = xp[(size_t)pf * (B_N*4)];
        // backpressure: don't overwrite slot until wave1 consumed t4i-8
        if (t4i >= 8u) { while (rdseen + 8u <= t4i) rdseen = *vrd; }
        float bases[4] = {xlo(xiv.x), xhi(xiv.x), xlo(xiv.y), xhi(xiv.y)};
        float hv[4];
#pragma unroll
        for (int ti = 0; ti < 4; ++ti) {
          float rs  = r;
          float rx1 = dppf<0xB1>(rs);   // quad_perm [1,0,3,2] : xor 1
          float rx2 = dppf<0x4E>(rs);   // quad_perm [2,3,0,1] : xor 2
          float rx3 = dppf<0x1B>(rs);   // quad_perm [3,2,1,0] : xor 3
          float pa = fmaf(u0, rs,  bases[ti]);
          float pb = fmaf(u1, rx1, pa);
          float pc = u2 * rx2;
          float pd = fmaf(u3, rx3, pc);
          float z  = pb + pd;
          float e  = __builtin_amdgcn_exp2f(z);
          r = __builtin_amdgcn_rcpf(e + 1.0f);
          hv[ti] = fmaf(-2.0f, r, 1.0f);        // off the serial chain
        }
        sring[t4i & 7u][lane] = make_uint2(pk2(hv[0], hv[1]), pk2(hv[2], hv[3]));
        // DS ops complete in order per wave: only block compiler reordering.
        __asm__ volatile("" ::: "memory");
        if (lane == 0) *vwr = t4i + 1u;
      }
    }
  } else {
    // ---------------- wave1: output MLP ----------------
    const int s = lane >> 2, tw = lane & 3;
    const size_t brow = (size_t)(blockIdx.x * 16 + s) * (size_t)T_N;
    float W3p0[6], W3p1[6], W3p2[6], W3p3[6], b3f[6], W4f[6];
#pragma unroll
    for (int m = 0; m < 6; ++m) {
      W3p0[m] = ldsel(W3, (tw    )*6 + m, f32);
      W3p1[m] = ldsel(W3, (tw ^ 1)*6 + m, f32);
      W3p2[m] = ldsel(W3, (tw ^ 2)*6 + m, f32);
      W3p3[m] = ldsel(W3, (tw ^ 3)*6 + m, f32);
      b3f[m]  = ldsel(b3, m, f32);
      W4f[m]  = ldsel(W4, m, f32);
    }
    const float b4f = ldsel(b4, 0, f32);

    u32 wrseen = 0;
    for (u32 t4i = 0; t4i < T_N/4; ++t4i) {
      if (wrseen <= t4i) { do { wrseen = *vwr; } while (wrseen <= t4i); }
      __asm__ volatile("" ::: "memory");
      uint2 v = sring[t4i & 7u][lane];
      __asm__ volatile("" ::: "memory");
      if (lane == 0) *vrd = t4i + 1u;     // DS in-order: read retired first

      // quad transpose: lane (s,tw) gathers h_j(t=tw) for j = tw^d.
      float h0 = sel_h(v, tw);                    // j = tw      (own)
      float h1 = dppf<0xB1>(sel_h(v, tw ^ 1));    // j = tw^1
      float h2 = dppf<0x4E>(sel_h(v, tw ^ 2));    // j = tw^2
      float h3 = dppf<0x1B>(sel_h(v, tw ^ 3));    // j = tw^3

      float a = b4f;
#pragma unroll
      for (int m = 0; m < 6; ++m) {
        float y = b3f[m];
        y = fmaf(h0, W3p0[m], y);
        y = fmaf(h1, W3p1[m], y);
        y = fmaf(h2, W3p2[m], y);
        y = fmaf(h3, W3p3[m], y);
        y = fmaxf(y, 0.f);
        a = fmaf(y, W4f[m], a);
      }
      const size_t t = brow + (size_t)t4i*4 + (size_t)tw;
      if (f32) ((float*)outp)[t] = a;
      else     ((u16*)outp)[t]   = f2bf(a);
    }
  }
}

extern "C" void kernel_launch(void* const* d_in, const int* in_sizes, int n_in,
                              void* d_out, int out_size, void* d_ws, size_t ws_size,
                              hipStream_t stream)
{
  u32* xi2 = (u32*)d_ws;                                        // 33.5 MB fp16

  k_xi  <<<4096, 256, 0, stream>>>(d_in[0], d_in[1], d_in[2], d_in[3], d_in[4],
                                   d_in[5], d_in[6], d_in[7], d_in[8], xi2);
  k_scan<<<128, 128, 0, stream>>>(d_in[0], d_in[8], xi2,
                                  d_in[9], d_in[10], d_in[11], d_in[12], d_out);
}